// Round 16
// baseline (101.078 us; speedup 1.0000x reference)
//
#include <hip/hip_runtime.h>
#include <hip/hip_bf16.h>
#include <hip/hip_fp16.h>
#include <stdint.h>

#define DIMK 256
#define DIMV 384
#define NSEQ 1024
#define NHEAD 6
#define ZCAP 192

typedef __attribute__((ext_vector_type(8))) short short8;
typedef __attribute__((ext_vector_type(4))) float floatx4;

__device__ __forceinline__ unsigned short f2b(float f){
  unsigned int x = __float_as_uint(f);
  return (unsigned short)((x + 0x7fffu + ((x >> 16) & 1u)) >> 16);
}
__device__ __forceinline__ unsigned int pack2(float a, float b){
  return (unsigned int)f2b(a) | ((unsigned int)f2b(b) << 16);
}
__device__ __forceinline__ float blo(unsigned int u){ return __uint_as_float(u << 16); }

// ---------------- fused pre-pass: proj (blocks 0..1023) + maskbits (1024..3071)
__global__ __launch_bounds__(256) void fused_pre_kernel(
    const float* __restrict__ Q, const float* __restrict__ V,
    const float* __restrict__ WQ, const float* __restrict__ WK,
    const float* __restrict__ bQ, const float* __restrict__ bK,
    const float* __restrict__ A,
    unsigned short* __restrict__ qhi, unsigned short* __restrict__ qlo,
    unsigned short* __restrict__ kf,
    unsigned long long* __restrict__ bm, unsigned short* __restrict__ bmp)
{
  int bid = blockIdx.x;
  if (bid >= 1024){
    int r = (bid - 1024) * 4 + (threadIdx.x >> 6);
    int lane = threadIdx.x & 63;
    const float* arow = A + (size_t)r * NSEQ;
    unsigned long long myw = 0;
    #pragma unroll
    for (int c = 0; c < 16; ++c){
      unsigned long long m = __ballot(arow[c * 64 + lane] > 0.5f);
      if (lane == c) myw = m;
    }
    int own = (lane < 16) ? __popcll(myw) : 0;
    int inc = own;
    #pragma unroll
    for (int o = 1; o < 16; o <<= 1){
      int t = __shfl_up(inc, o, 16);
      if ((lane & 15) >= o) inc += t;
    }
    if (lane < 16){
      bm [(size_t)r * 16 + lane] = myw;
      bmp[(size_t)r * 16 + lane] = (unsigned short)(inc - own);
    }
    return;
  }

  __shared__ uint4 lA[512];
  __shared__ unsigned short lB16[96 * 72];
  int which = bid >> 9;
  int rem = bid & 511;
  int bx = rem >> 2, by = rem & 3;
  const float* X = which ? V : Q;
  const float* W = which ? WK : WQ;
  const float* bias = which ? bK : bQ;

  int t = threadIdx.x;
  int lane = t & 63, wave = t >> 6;
  int wm = wave >> 1, wn = wave & 1;
  int rb = bx * 64;
  int nb = by * 96;
  floatx4 acc[2][3];
  #pragma unroll
  for (int mi = 0; mi < 2; ++mi)
    #pragma unroll
    for (int ni = 0; ni < 3; ++ni) acc[mi][ni] = (floatx4){0.f, 0.f, 0.f, 0.f};

  for (int it = 0; it < 4; ++it){
    int k0 = it * 64;
    #pragma unroll
    for (int i = 0; i < 2; ++i){
      int c = t + i * 256;
      int kc = c >> 6, row = c & 63;
      const float* src = X + (size_t)(rb + row) * DIMK + k0 + kc * 8;
      float4 f0 = *(const float4*)src;
      float4 f1 = *(const float4*)(src + 4);
      uint4 w;
      w.x = pack2(f0.x, f0.y); w.y = pack2(f0.z, f0.w);
      w.z = pack2(f1.x, f1.y); w.w = pack2(f1.z, f1.w);
      lA[c] = w;
    }
    #pragma unroll
    for (int i = 0; i < 6; ++i){
      int c = t + i * 256;
      int kk2 = c / 24, f4 = c % 24;
      float4 wv = *(const float4*)(W + (size_t)(k0 + kk2) * DIMV + nb + f4 * 4);
      int n0 = f4 * 4;
      lB16[(n0    ) * 72 + kk2] = f2b(wv.x);
      lB16[(n0 + 1) * 72 + kk2] = f2b(wv.y);
      lB16[(n0 + 2) * 72 + kk2] = f2b(wv.z);
      lB16[(n0 + 3) * 72 + kk2] = f2b(wv.w);
    }
    __syncthreads();
    #pragma unroll
    for (int kk = 0; kk < 2; ++kk){
      int kc  = kk * 4 + (lane >> 4);
      int r16 = lane & 15;
      short8 af[2], bf[3];
      #pragma unroll
      for (int mi = 0; mi < 2; ++mi)
        af[mi] = *(const short8*)&lA[kc * 64 + wm * 32 + mi * 16 + r16];
      #pragma unroll
      for (int ni = 0; ni < 3; ++ni)
        bf[ni] = *(const short8*)&lB16[(wn * 48 + ni * 16 + r16) * 72 + kc * 8];
      #pragma unroll
      for (int mi = 0; mi < 2; ++mi)
        #pragma unroll
        for (int ni = 0; ni < 3; ++ni)
          acc[mi][ni] = __builtin_amdgcn_mfma_f32_16x16x32_bf16(af[mi], bf[ni], acc[mi][ni], 0, 0, 0);
    }
    __syncthreads();
  }
  const float scale = 0.05103103630798288f;
  int r16 = lane & 15, rq = lane >> 4;
  #pragma unroll
  for (int ni = 0; ni < 3; ++ni){
    int col = nb + wn * 48 + ni * 16 + r16;
    float bv = bias[col];
    int h = col >> 6, d = col & 63;
    #pragma unroll
    for (int mi = 0; mi < 2; ++mi){
      #pragma unroll
      for (int q = 0; q < 4; ++q){
        int row = rb + wm * 32 + mi * 16 + rq * 4 + q;
        int bb = row >> 10, n = row & 1023;
        int slice = bb * NHEAD + h;
        size_t dst = ((((size_t)slice * 2 + (d >> 5)) * 64 + (n >> 4)) * 64
                      + ((d >> 3) & 3) * 16 + (n & 15)) * 8 + (d & 7);
        float v = acc[mi][ni][q] + bv;
        if (which){
          kf[dst] = f2b(v);
        } else {
          v *= scale;
          unsigned short hi_ = f2b(v);
          qhi[dst] = hi_;
          qlo[dst] = f2b(v - blo((unsigned int)hi_));
        }
      }
    }
  }
}

__device__ __forceinline__ void red2(float& a, float& b){
  #pragma unroll
  for (int o = 1; o < 64; o <<= 1){ a += __shfl_xor(a, o); b += __shfl_xor(b, o); }
}
__device__ __forceinline__ void red4(float& a, float& b, float& c, float& d){
  #pragma unroll
  for (int o = 1; o < 64; o <<= 1){
    a += __shfl_xor(a, o); b += __shfl_xor(b, o);
    c += __shfl_xor(c, o); d += __shfl_xor(d, o);
  }
}

// ---- Phase A: MFMA + masked compaction -> global f16 zg (no epilogue) ----
__global__ __launch_bounds__(512) void attn_mfma_kernel(
    const unsigned short* __restrict__ qhi, const unsigned short* __restrict__ qlo,
    const unsigned short* __restrict__ kf, const unsigned long long* __restrict__ bm,
    const unsigned short* __restrict__ bmp, __half* __restrict__ zg)
{
  __shared__ unsigned long long mw[16][16];
  __shared__ unsigned short    mp[16][16];

  int bid = blockIdx.x;
  int x = bid & 7;
  int u = bid >> 3;
  int h = u >> 6;
  int rb = u & 63;
  int tid = threadIdx.x;
  int lane = tid & 63, w = tid >> 6;
  int slice = x * NHEAD + h;
  int rowbase = (x << 10) + (rb << 4);

  if (tid < 256){
    int rr = tid >> 4, ww = tid & 15;
    mw[rr][ww] = bm [((size_t)(rowbase + rr)) * 16 + ww];
    mp[rr][ww] = bmp[((size_t)(rowbase + rr)) * 16 + ww];
  }

  const short8* qh8 = (const short8*)qhi;
  const short8* ql8 = (const short8*)qlo;
  const short8* kf8 = (const short8*)kf;
  size_t ab0 = (((size_t)slice * 2 + 0) * 64 + rb) * 64 + lane;
  size_t ab1 = (((size_t)slice * 2 + 1) * 64 + rb) * 64 + lane;
  short8 ah0 = qh8[ab0], al0 = ql8[ab0];
  short8 ah1 = qh8[ab1], al1 = ql8[ab1];
  __syncthreads();

  size_t zslice = (size_t)slice * NSEQ;
  __builtin_amdgcn_s_setprio(1);
  #pragma unroll
  for (int i = 0; i < 8; ++i){
    int tt = (w << 3) + i;
    short8 b0 = kf8[(((size_t)slice * 2 + 0) * 64 + tt) * 64 + lane];
    short8 b1 = kf8[(((size_t)slice * 2 + 1) * 64 + tt) * 64 + lane];
    floatx4 a = (floatx4){0.f, 0.f, 0.f, 0.f};
    a = __builtin_amdgcn_mfma_f32_16x16x32_bf16(al0, b0, a, 0, 0, 0);
    a = __builtin_amdgcn_mfma_f32_16x16x32_bf16(ah0, b0, a, 0, 0, 0);
    a = __builtin_amdgcn_mfma_f32_16x16x32_bf16(al1, b1, a, 0, 0, 0);
    a = __builtin_amdgcn_mfma_f32_16x16x32_bf16(ah1, b1, a, 0, 0, 0);
    int colb = (w << 7) + (i << 4) + (lane & 15);
    int cw = colb >> 6, cb = colb & 63;
    unsigned long long below = (1ull << cb) - 1ull;
    #pragma unroll
    for (int reg = 0; reg < 4; ++reg){
      int rowz = ((lane >> 4) << 2) + reg;
      unsigned long long word = mw[rowz][cw];
      if ((word >> cb) & 1){
        int rank = (int)mp[rowz][cw] + __popcll(word & below);
        if (rank < ZCAP)
          zg[(zslice + (rb << 4) + rowz) * ZCAP + rank] = __float2half(a[reg]);
      }
    }
  }
  __builtin_amdgcn_s_setprio(0);
}

// ---- Phase B: barrier-free sparsemax + dense streaming store ----
// 256 thr, 4 waves, each wave fully independent on 2 row-instances.
__global__ __launch_bounds__(256) void sparsemax_kernel(
    const __half* __restrict__ zg, const unsigned long long* __restrict__ bm,
    const unsigned short* __restrict__ bmp, float* __restrict__ out)
{
  __shared__ float             zl[8][ZCAP + 1];
  __shared__ unsigned long long mwL[8][16];
  __shared__ unsigned short    mpL[8][16];

  int bid = blockIdx.x;
  int x = bid & 7;            // batch == XCD (matches zg producer)
  int u = bid >> 3;           // 0..767
  int h = u >> 7;             // head
  int rg = u & 127;           // 8-row group
  int tid = threadIdx.x;
  int lane = tid & 63, w = tid >> 6;
  int slice = x * NHEAD + h;
  int n0 = (rg << 3) + (w << 1);
  int l0 = (w << 1), l1 = l0 + 1;

  // wave-local mask load (no cross-wave sharing -> no barrier)
  if (lane < 32){
    int rr = lane >> 4, wi = lane & 15;
    size_t rowg = (size_t)(x << 10) + n0 + rr;
    mwL[l0 + rr][wi] = bm [rowg * 16 + wi];
    mpL[l0 + rr][wi] = bmp[rowg * 16 + wi];
  }
  int M0 = (int)mpL[l0][15] + __popcll(mwL[l0][15]);
  int M1 = (int)mpL[l1][15] + __popcll(mwL[l1][15]);

  size_t zb0 = ((size_t)slice * NSEQ + n0) * ZCAP;
  size_t zb1 = zb0 + ZCAP;
  float z0a = 0.f, z0b = 0.f, z0c = 0.f, z1a = 0.f, z1b = 0.f, z1c = 0.f;
  if (lane < M0){ z0a = __half2float(zg[zb0 + lane]); zl[l0][lane] = z0a; }
  if (lane < M1){ z1a = __half2float(zg[zb1 + lane]); zl[l1][lane] = z1a; }
  if (M0 > 64 && 64 + lane < M0){ z0b = __half2float(zg[zb0 + 64 + lane]); zl[l0][64 + lane] = z0b; }
  if (M1 > 64 && 64 + lane < M1){ z1b = __half2float(zg[zb1 + 64 + lane]); zl[l1][64 + lane] = z1b; }
  if (M0 > 128 && 128 + lane < M0){ z0c = __half2float(zg[zb0 + 128 + lane]); zl[l0][128 + lane] = z0c; }
  if (M1 > 128 && 128 + lane < M1){ z1c = __half2float(zg[zb1 + 128 + lane]); zl[l1][128 + lane] = z1c; }

  float tau0, tau1;
  if (M0 <= 64 && M1 <= 64){
    bool a0 = lane < M0, a1 = lane < M1;
    float s0 = z0a, s1 = z1a;          // inactive lanes already 0
    red2(s0, s1);
    tau0 = (s0 - 1.f) / (float)M0;
    tau1 = (s1 - 1.f) / (float)M1;
    int p0 = M0, p1 = M1;
    #pragma unroll 1
    for (int it = 0; it < 32; ++it){
      bool i0 = a0 && z0a > tau0, i1 = a1 && z1a > tau1;
      int n0c = __popcll(__ballot(i0));
      int n1c = __popcll(__ballot(i1));
      s0 = i0 ? z0a : 0.f; s1 = i1 ? z1a : 0.f;
      red2(s0, s1);
      bool stable = (n0c == p0) && (n1c == p1);
      tau0 = (s0 - 1.f) / (float)n0c;
      tau1 = (s1 - 1.f) / (float)n1c;
      p0 = n0c; p1 = n1c;
      if (stable) break;
    }
  } else {
    bool a0 = lane < M0, b0_ = 64 + lane < M0, c0_ = 128 + lane < M0;
    bool a1 = lane < M1, b1_ = 64 + lane < M1, c1_ = 128 + lane < M1;
    float s0 = z0a + z0b + z0c;
    float n0c = (a0 ? 1.f : 0.f) + (b0_ ? 1.f : 0.f) + (c0_ ? 1.f : 0.f);
    float s1 = z1a + z1b + z1c;
    float n1c = (a1 ? 1.f : 0.f) + (b1_ ? 1.f : 0.f) + (c1_ ? 1.f : 0.f);
    red4(s0, n0c, s1, n1c);
    tau0 = (s0 - 1.f) / n0c; tau1 = (s1 - 1.f) / n1c;
    float p0 = n0c, p1 = n1c;
    #pragma unroll 1
    for (int it = 0; it < 32; ++it){
      bool i0a = a0 && z0a > tau0, i0b = b0_ && z0b > tau0, i0c = c0_ && z0c > tau0;
      bool i1a = a1 && z1a > tau1, i1b = b1_ && z1b > tau1, i1c = c1_ && z1c > tau1;
      s0 = (i0a ? z0a : 0.f) + (i0b ? z0b : 0.f) + (i0c ? z0c : 0.f);
      n0c = (i0a ? 1.f : 0.f) + (i0b ? 1.f : 0.f) + (i0c ? 1.f : 0.f);
      s1 = (i1a ? z1a : 0.f) + (i1b ? z1b : 0.f) + (i1c ? z1c : 0.f);
      n1c = (i1a ? 1.f : 0.f) + (i1b ? 1.f : 0.f) + (i1c ? 1.f : 0.f);
      red4(s0, n0c, s1, n1c);
      bool stable = (n0c == p0) && (n1c == p1);
      tau0 = (s0 - 1.f) / n0c; tau1 = (s1 - 1.f) / n1c;
      p0 = n0c; p1 = n1c;
      if (stable) break;
    }
  }

  // dense output, vectorized rank-walk (reads zl, same-wave LDS ordering)
  float* o0 = out + ((size_t)((x << 10) + n0) * NHEAD + h) * NSEQ;
  float* o1 = o0 + (size_t)NHEAD * NSEQ;
  int b0v = (lane & 15) << 2;
  unsigned long long pmask = (1ull << b0v) - 1ull;
  #pragma unroll
  for (int qtr = 0; qtr < 4; ++qtr){
    int cw = (qtr << 2) + (lane >> 4);
    unsigned long long w0 = mwL[l0][cw], w1 = mwL[l1][cw];
    int rk0 = (int)mpL[l0][cw] + __popcll(w0 & pmask);
    int rk1 = (int)mpL[l1][cw] + __popcll(w1 & pmask);
    float v0[4], v1[4];
    #pragma unroll
    for (int j = 0; j < 4; ++j){
      int bit0 = (int)((w0 >> (b0v + j)) & 1ull);
      int bit1 = (int)((w1 >> (b0v + j)) & 1ull);
      v0[j] = bit0 ? fmaxf(zl[l0][rk0] - tau0, 0.f) : 0.f;
      v1[j] = bit1 ? fmaxf(zl[l1][rk1] - tau1, 0.f) : 0.f;
      rk0 += bit0; rk1 += bit1;
    }
    ((float4*)o0)[(qtr << 6) + lane] = make_float4(v0[0], v0[1], v0[2], v0[3]);
    ((float4*)o1)[(qtr << 6) + lane] = make_float4(v1[0], v1[1], v1[2], v1[3]);
  }
}

// ---- Fallback: r13's fused attn (used when ws_size can't fit zg) ----
__global__ __launch_bounds__(512) void attn_kernel(
    const unsigned short* __restrict__ qhi, const unsigned short* __restrict__ qlo,
    const unsigned short* __restrict__ kf, const unsigned long long* __restrict__ bm,
    const unsigned short* __restrict__ bmp, float* __restrict__ out)
{
  __shared__ unsigned long long mw[16][16];
  __shared__ unsigned short    mp[16][16];
  __shared__ float             zlds[16][ZCAP + 1];

  int bid = blockIdx.x;
  int x = bid & 7;
  int u = bid >> 3;
  int h = u >> 6;
  int rb = u & 63;
  int tid = threadIdx.x;
  int lane = tid & 63, w = tid >> 6;
  int slice = x * NHEAD + h;
  int rowbase = (x << 10) + (rb << 4);

  if (tid < 256){
    int rr = tid >> 4, ww = tid & 15;
    mw[rr][ww] = bm [((size_t)(rowbase + rr)) * 16 + ww];
    mp[rr][ww] = bmp[((size_t)(rowbase + rr)) * 16 + ww];
  }
  const short8* qh8 = (const short8*)qhi;
  const short8* ql8 = (const short8*)qlo;
  const short8* kf8 = (const short8*)kf;
  size_t ab0 = (((size_t)slice * 2 + 0) * 64 + rb) * 64 + lane;
  size_t ab1 = (((size_t)slice * 2 + 1) * 64 + rb) * 64 + lane;
  short8 ah0 = qh8[ab0], al0 = ql8[ab0];
  short8 ah1 = qh8[ab1], al1 = ql8[ab1];
  __syncthreads();

  __builtin_amdgcn_s_setprio(1);
  #pragma unroll
  for (int i = 0; i < 8; ++i){
    int tt = (w << 3) + i;
    short8 b0 = kf8[(((size_t)slice * 2 + 0) * 64 + tt) * 64 + lane];
    short8 b1 = kf8[(((size_t)slice * 2 + 1) * 64 + tt) * 64 + lane];
    floatx4 a = (floatx4){0.f, 0.f, 0.f, 0.f};
    a = __builtin_amdgcn_mfma_f32_16x16x32_bf16(al0, b0, a, 0, 0, 0);
    a = __builtin_amdgcn_mfma_f32_16x16x32_bf16(ah0, b0, a, 0, 0, 0);
    a = __builtin_amdgcn_mfma_f32_16x16x32_bf16(al1, b1, a, 0, 0, 0);
    a = __builtin_amdgcn_mfma_f32_16x16x32_bf16(ah1, b1, a, 0, 0, 0);
    int colb = (w << 7) + (i << 4) + (lane & 15);
    int cw = colb >> 6, cb = colb & 63;
    unsigned long long below = (1ull << cb) - 1ull;
    #pragma unroll
    for (int reg = 0; reg < 4; ++reg){
      int rowz = ((lane >> 4) << 2) + reg;
      unsigned long long word = mw[rowz][cw];
      if ((word >> cb) & 1){
        int rank = (int)mp[rowz][cw] + __popcll(word & below);
        if (rank < ZCAP) zlds[rowz][rank] = a[reg];
      }
    }
  }
  __builtin_amdgcn_s_setprio(0);
  __syncthreads();

  int row0 = w * 2, row1 = w * 2 + 1;
  int M0 = (int)mp[row0][15] + __popcll(mw[row0][15]);
  int M1 = (int)mp[row1][15] + __popcll(mw[row1][15]);
  float tau0, tau1;

  if (M0 <= 64 && M1 <= 64){
    bool a0 = lane < M0, a1 = lane < M1;
    float z0 = a0 ? zlds[row0][lane] : 0.f;
    float z1 = a1 ? zlds[row1][lane] : 0.f;
    float s0 = z0, s1 = z1;
    red2(s0, s1);
    tau0 = (s0 - 1.f) / (float)M0;
    tau1 = (s1 - 1.f) / (float)M1;
    int p0 = M0, p1 = M1;
    #pragma unroll 1
    for (int it = 0; it < 32; ++it){
      bool i0 = a0 && z0 > tau0, i1 = a1 && z1 > tau1;
      int n0 = __popcll(__ballot(i0));
      int n1 = __popcll(__ballot(i1));
      s0 = i0 ? z0 : 0.f; s1 = i1 ? z1 : 0.f;
      red2(s0, s1);
      bool stable = (n0 == p0) && (n1 == p1);
      tau0 = (s0 - 1.f) / (float)n0;
      tau1 = (s1 - 1.f) / (float)n1;
      p0 = n0; p1 = n1;
      if (stable) break;
    }
  } else {
    float z0a = (lane < M0)       ? zlds[row0][lane]       : 0.f;
    float z1a = (lane < M1)       ? zlds[row1][lane]       : 0.f;
    float z0b = (64 + lane < M0)  ? zlds[row0][64 + lane]  : 0.f;
    float z1b = (64 + lane < M1)  ? zlds[row1][64 + lane]  : 0.f;
    float z0c = (128 + lane < M0) ? zlds[row0][128 + lane] : 0.f;
    float z1c = (128 + lane < M1) ? zlds[row1][128 + lane] : 0.f;
    bool a0 = lane < M0, b0_ = 64 + lane < M0, c0_ = 128 + lane < M0;
    bool a1 = lane < M1, b1_ = 64 + lane < M1, c1_ = 128 + lane < M1;
    float s0 = (a0 ? z0a : 0.f) + (b0_ ? z0b : 0.f) + (c0_ ? z0c : 0.f);
    float n0 = (a0 ? 1.f : 0.f) + (b0_ ? 1.f : 0.f) + (c0_ ? 1.f : 0.f);
    float s1 = (a1 ? z1a : 0.f) + (b1_ ? z1b : 0.f) + (c1_ ? z1c : 0.f);
    float n1 = (a1 ? 1.f : 0.f) + (b1_ ? 1.f : 0.f) + (c1_ ? 1.f : 0.f);
    red4(s0, n0, s1, n1);
    tau0 = (s0 - 1.f) / n0; tau1 = (s1 - 1.f) / n1;
    float p0 = n0, p1 = n1;
    #pragma unroll 1
    for (int it = 0; it < 32; ++it){
      bool i0a = a0 && z0a > tau0, i0b = b0_ && z0b > tau0, i0c = c0_ && z0c > tau0;
      bool i1a = a1 && z1a > tau1, i1b = b1_ && z1b > tau1, i1c = c1_ && z1c > tau1;
      s0 = (i0a ? z0a : 0.f) + (i0b ? z0b : 0.f) + (i0c ? z0c : 0.f);
      n0 = (i0a ? 1.f : 0.f) + (i0b ? 1.f : 0.f) + (i0c ? 1.f : 0.f);
      s1 = (i1a ? z1a : 0.f) + (i1b ? z1b : 0.f) + (i1c ? z1c : 0.f);
      n1 = (i1a ? 1.f : 0.f) + (i1b ? 1.f : 0.f) + (i1c ? 1.f : 0.f);
      red4(s0, n0, s1, n1);
      bool stable = (n0 == p0) && (n1 == p1);
      tau0 = (s0 - 1.f) / n0; tau1 = (s1 - 1.f) / n1;
      p0 = n0; p1 = n1;
      if (stable) break;
    }
  }

  float* o0 = out + ((size_t)(rowbase + row0) * NHEAD + h) * NSEQ;
  float* o1 = out + ((size_t)(rowbase + row1) * NHEAD + h) * NSEQ;
  int b0v = (lane & 15) << 2;
  unsigned long long pmask = (1ull << b0v) - 1ull;
  #pragma unroll
  for (int qtr = 0; qtr < 4; ++qtr){
    int cw = (qtr << 2) + (lane >> 4);
    unsigned long long w0 = mw[row0][cw], w1 = mw[row1][cw];
    int rk0 = (int)mp[row0][cw] + __popcll(w0 & pmask);
    int rk1 = (int)mp[row1][cw] + __popcll(w1 & pmask);
    float v0[4], v1[4];
    #pragma unroll
    for (int j = 0; j < 4; ++j){
      int bit0 = (int)((w0 >> (b0v + j)) & 1ull);
      int bit1 = (int)((w1 >> (b0v + j)) & 1ull);
      v0[j] = bit0 ? fmaxf(zlds[row0][rk0] - tau0, 0.f) : 0.f;
      v1[j] = bit1 ? fmaxf(zlds[row1][rk1] - tau1, 0.f) : 0.f;
      rk0 += bit0; rk1 += bit1;
    }
    ((float4*)o0)[(qtr << 6) + lane] = make_float4(v0[0], v0[1], v0[2], v0[3]);
    ((float4*)o1)[(qtr << 6) + lane] = make_float4(v1[0], v1[1], v1[2], v1[3]);
  }
}

extern "C" void kernel_launch(void* const* d_in, const int* in_sizes, int n_in,
                              void* d_out, int out_size, void* d_ws, size_t ws_size,
                              hipStream_t stream) {
  const float* Q  = (const float*)d_in[0];
  const float* V  = (const float*)d_in[1];
  const float* A  = (const float*)d_in[2];
  const float* WQ = (const float*)d_in[3];
  const float* bQ = (const float*)d_in[4];
  const float* WK = (const float*)d_in[5];
  const float* bK = (const float*)d_in[6];
  float* out = (float*)d_out;

  char* ws = (char*)d_ws;
  unsigned short*     qhi = (unsigned short*)ws;                          // 6.29 MB
  unsigned short*     qlo = (unsigned short*)(ws + (size_t)6291456);      // 6.29 MB
  unsigned short*     kf  = (unsigned short*)(ws + (size_t)12582912);     // 6.29 MB
  unsigned long long* bm  = (unsigned long long*)(ws + (size_t)19267584); // 1.05 MB
  unsigned short*     bmp = (unsigned short*)(ws + (size_t)20316160);     // 0.26 MB
  __half*             zg  = (__half*)(ws + (size_t)20578304);             // 18.87 MB
  const size_t WS_NEEDED_SPLIT = 20578304 + (size_t)48 * 1024 * ZCAP * 2; // ~39.45 MB
  (void)in_sizes; (void)n_in; (void)out_size;

  fused_pre_kernel<<<3072, 256, 0, stream>>>(Q, V, WQ, WK, bQ, bK, A,
                                             qhi, qlo, kf, bm, bmp);
  if (ws_size >= WS_NEEDED_SPLIT){
    attn_mfma_kernel<<<3072, 512, 0, stream>>>(qhi, qlo, kf, bm, bmp, zg);
    sparsemax_kernel<<<6144, 256, 0, stream>>>(zg, bm, bmp, out);
  } else {
    attn_kernel<<<3072, 512, 0, stream>>>(qhi, qlo, kf, bm, bmp, out);
  }
}

// Round 17
// 81.245 us; speedup vs baseline: 1.2441x; 1.2441x over previous
//
#include <hip/hip_runtime.h>
#include <hip/hip_bf16.h>
#include <stdint.h>

#define DIMK 256
#define DIMV 384
#define NSEQ 1024
#define NHEAD 6
#define ZCAP 192

typedef __attribute__((ext_vector_type(8))) short short8;
typedef __attribute__((ext_vector_type(4))) float floatx4;

__device__ __forceinline__ unsigned short f2b(float f){
  unsigned int x = __float_as_uint(f);
  return (unsigned short)((x + 0x7fffu + ((x >> 16) & 1u)) >> 16);
}
__device__ __forceinline__ unsigned int pack2(float a, float b){
  return (unsigned int)f2b(a) | ((unsigned int)f2b(b) << 16);
}

// ---------------- fused pre-pass: proj (blocks 0..1023) + maskbits (1024..3071)
// proj: fragment-major q (bf16, pre-scaled by 1/sqrt(384)) and k (bf16).
// frag coords for (seq n, feature d, slice=b*6+h):
//   dst = (((slice*2 + (d>>5))*64 + (n>>4))*64 + ((d>>3)&3)*16 + (n&15))*8 + (d&7)
__global__ __launch_bounds__(256) void fused_pre_kernel(
    const float* __restrict__ Q, const float* __restrict__ V,
    const float* __restrict__ WQ, const float* __restrict__ WK,
    const float* __restrict__ bQ, const float* __restrict__ bK,
    const float* __restrict__ A,
    unsigned short* __restrict__ qf, unsigned short* __restrict__ kf,
    unsigned long long* __restrict__ bm, unsigned short* __restrict__ bmp)
{
  int bid = blockIdx.x;
  if (bid >= 1024){
    // ---- maskbits: A -> row bitmask + exclusive word-prefix popcounts ----
    int r = (bid - 1024) * 4 + (threadIdx.x >> 6);
    int lane = threadIdx.x & 63;
    const float* arow = A + (size_t)r * NSEQ;
    unsigned long long myw = 0;
    #pragma unroll
    for (int c = 0; c < 16; ++c){
      unsigned long long m = __ballot(arow[c * 64 + lane] > 0.5f);
      if (lane == c) myw = m;
    }
    int own = (lane < 16) ? __popcll(myw) : 0;
    int inc = own;
    #pragma unroll
    for (int o = 1; o < 16; o <<= 1){
      int t = __shfl_up(inc, o, 16);
      if ((lane & 15) >= o) inc += t;
    }
    if (lane < 16){
      bm [(size_t)r * 16 + lane] = myw;
      bmp[(size_t)r * 16 + lane] = (unsigned short)(inc - own);
    }
    return;
  }

  // ---- proj path ----
  __shared__ uint4 lA[512];                    // [kc 0..7][row 0..63]
  __shared__ unsigned short lB16[96 * 72];     // [n 0..95][k 0..63, pitch 72]
  int which = bid >> 9;                        // 0: q, 1: k
  int rem = bid & 511;
  int bx = rem >> 2, by = rem & 3;
  const float* X = which ? V : Q;
  const float* W = which ? WK : WQ;
  const float* bias = which ? bK : bQ;

  int t = threadIdx.x;
  int lane = t & 63, wave = t >> 6;
  int wm = wave >> 1, wn = wave & 1;
  int rb = bx * 64;
  int nb = by * 96;
  floatx4 acc[2][3];
  #pragma unroll
  for (int mi = 0; mi < 2; ++mi)
    #pragma unroll
    for (int ni = 0; ni < 3; ++ni) acc[mi][ni] = (floatx4){0.f, 0.f, 0.f, 0.f};

  for (int it = 0; it < 4; ++it){
    int k0 = it * 64;
    #pragma unroll
    for (int i = 0; i < 2; ++i){
      int c = t + i * 256;
      int kc = c >> 6, row = c & 63;
      const float* src = X + (size_t)(rb + row) * DIMK + k0 + kc * 8;
      float4 f0 = *(const float4*)src;
      float4 f1 = *(const float4*)(src + 4);
      uint4 w;
      w.x = pack2(f0.x, f0.y); w.y = pack2(f0.z, f0.w);
      w.z = pack2(f1.x, f1.y); w.w = pack2(f1.z, f1.w);
      lA[c] = w;
    }
    #pragma unroll
    for (int i = 0; i < 6; ++i){
      int c = t + i * 256;
      int kk2 = c / 24, f4 = c % 24;
      float4 wv = *(const float4*)(W + (size_t)(k0 + kk2) * DIMV + nb + f4 * 4);
      int n0 = f4 * 4;
      lB16[(n0    ) * 72 + kk2] = f2b(wv.x);
      lB16[(n0 + 1) * 72 + kk2] = f2b(wv.y);
      lB16[(n0 + 2) * 72 + kk2] = f2b(wv.z);
      lB16[(n0 + 3) * 72 + kk2] = f2b(wv.w);
    }
    __syncthreads();
    #pragma unroll
    for (int kk = 0; kk < 2; ++kk){
      int kc  = kk * 4 + (lane >> 4);
      int r16 = lane & 15;
      short8 af[2], bf[3];
      #pragma unroll
      for (int mi = 0; mi < 2; ++mi)
        af[mi] = *(const short8*)&lA[kc * 64 + wm * 32 + mi * 16 + r16];
      #pragma unroll
      for (int ni = 0; ni < 3; ++ni)
        bf[ni] = *(const short8*)&lB16[(wn * 48 + ni * 16 + r16) * 72 + kc * 8];
      #pragma unroll
      for (int mi = 0; mi < 2; ++mi)
        #pragma unroll
        for (int ni = 0; ni < 3; ++ni)
          acc[mi][ni] = __builtin_amdgcn_mfma_f32_16x16x32_bf16(af[mi], bf[ni], acc[mi][ni], 0, 0, 0);
    }
    __syncthreads();
  }
  const float scale = 0.05103103630798288f;    // 1/sqrt(384), folded into q
  int r16 = lane & 15, rq = lane >> 4;
  #pragma unroll
  for (int ni = 0; ni < 3; ++ni){
    int col = nb + wn * 48 + ni * 16 + r16;
    float bv = bias[col];
    int h = col >> 6, d = col & 63;
    #pragma unroll
    for (int mi = 0; mi < 2; ++mi){
      #pragma unroll
      for (int q = 0; q < 4; ++q){
        int row = rb + wm * 32 + mi * 16 + rq * 4 + q;
        int bb = row >> 10, n = row & 1023;
        int slice = bb * NHEAD + h;
        size_t dst = ((((size_t)slice * 2 + (d >> 5)) * 64 + (n >> 4)) * 64
                      + ((d >> 3) & 3) * 16 + (n & 15)) * 8 + (d & 7);
        float v = acc[mi][ni][q] + bv;
        if (which) kf[dst] = f2b(v);
        else       qf[dst] = f2b(v * scale);
      }
    }
  }
}

__device__ __forceinline__ void red2(float& a, float& b){
  #pragma unroll
  for (int o = 1; o < 64; o <<= 1){ a += __shfl_xor(a, o); b += __shfl_xor(b, o); }
}
__device__ __forceinline__ void red4(float& a, float& b, float& c, float& d){
  #pragma unroll
  for (int o = 1; o < 64; o <<= 1){
    a += __shfl_xor(a, o); b += __shfl_xor(b, o);
    c += __shfl_xor(c, o); d += __shfl_xor(d, o);
  }
}

// Dense MFMA attn with COMPACTED logits (r13 structure), single-bf16 q:
// 2 MFMAs per k-tile instead of 4 (hi/lo split dropped; error budget holds).
__global__ __launch_bounds__(512) void attn_kernel(
    const unsigned short* __restrict__ qf, const unsigned short* __restrict__ kf,
    const unsigned long long* __restrict__ bm, const unsigned short* __restrict__ bmp,
    float* __restrict__ out)
{
  __shared__ unsigned long long mw[16][16];
  __shared__ unsigned short    mp[16][16];
  __shared__ float             zlds[16][ZCAP + 1];

  int bid = blockIdx.x;
  int x = bid & 7;            // batch == XCD
  int u = bid >> 3;           // 0..383
  int h = u >> 6;             // head
  int rb = u & 63;            // 16-row block
  int tid = threadIdx.x;
  int lane = tid & 63, w = tid >> 6;
  int slice = x * NHEAD + h;
  int rowbase = (x << 10) + (rb << 4);

  if (tid < 256){
    int rr = tid >> 4, ww = tid & 15;
    mw[rr][ww] = bm [((size_t)(rowbase + rr)) * 16 + ww];
    mp[rr][ww] = bmp[((size_t)(rowbase + rr)) * 16 + ww];
  }

  const short8* qf8 = (const short8*)qf;
  const short8* kf8 = (const short8*)kf;
  size_t ab0 = (((size_t)slice * 2 + 0) * 64 + rb) * 64 + lane;
  size_t ab1 = (((size_t)slice * 2 + 1) * 64 + rb) * 64 + lane;
  short8 ah0 = qf8[ab0];
  short8 ah1 = qf8[ab1];
  __syncthreads();

  __builtin_amdgcn_s_setprio(1);
  #pragma unroll
  for (int i = 0; i < 8; ++i){
    int tt = (w << 3) + i;
    short8 b0 = kf8[(((size_t)slice * 2 + 0) * 64 + tt) * 64 + lane];
    short8 b1 = kf8[(((size_t)slice * 2 + 1) * 64 + tt) * 64 + lane];
    floatx4 a = (floatx4){0.f, 0.f, 0.f, 0.f};
    a = __builtin_amdgcn_mfma_f32_16x16x32_bf16(ah0, b0, a, 0, 0, 0);
    a = __builtin_amdgcn_mfma_f32_16x16x32_bf16(ah1, b1, a, 0, 0, 0);
    int colb = (w << 7) + (i << 4) + (lane & 15);
    int cw = colb >> 6, cb = colb & 63;
    unsigned long long below = (1ull << cb) - 1ull;
    #pragma unroll
    for (int reg = 0; reg < 4; ++reg){
      int rowz = ((lane >> 4) << 2) + reg;       // C/D: col=lane&15, row=(lane>>4)*4+reg
      unsigned long long word = mw[rowz][cw];
      if ((word >> cb) & 1){
        int rank = (int)mp[rowz][cw] + __popcll(word & below);
        if (rank < ZCAP) zlds[rowz][rank] = a[reg];
      }
    }
  }
  __builtin_amdgcn_s_setprio(0);
  __syncthreads();

  int row0 = w * 2, row1 = w * 2 + 1;
  int M0 = (int)mp[row0][15] + __popcll(mw[row0][15]);
  int M1 = (int)mp[row1][15] + __popcll(mw[row1][15]);
  float tau0, tau1;

  if (M0 <= 64 && M1 <= 64){
    // ---- fast path (94%): 1 chunk, ballot counts, red2 ----
    bool a0 = lane < M0, a1 = lane < M1;
    float z0 = a0 ? zlds[row0][lane] : 0.f;
    float z1 = a1 ? zlds[row1][lane] : 0.f;
    float s0 = z0, s1 = z1;
    red2(s0, s1);
    tau0 = (s0 - 1.f) / (float)M0;
    tau1 = (s1 - 1.f) / (float)M1;
    int p0 = M0, p1 = M1;
    #pragma unroll 1
    for (int it = 0; it < 32; ++it){
      bool i0 = a0 && z0 > tau0, i1 = a1 && z1 > tau1;
      int n0 = __popcll(__ballot(i0));
      int n1 = __popcll(__ballot(i1));
      s0 = i0 ? z0 : 0.f; s1 = i1 ? z1 : 0.f;
      red2(s0, s1);
      bool stable = (n0 == p0) && (n1 == p1);
      tau0 = (s0 - 1.f) / (float)n0;
      tau1 = (s1 - 1.f) / (float)n1;
      p0 = n0; p1 = n1;
      if (stable) break;
    }
  } else {
    // ---- generic path: 3 register chunks (cap 192) ----
    float z0a = (lane < M0)       ? zlds[row0][lane]       : 0.f;
    float z1a = (lane < M1)       ? zlds[row1][lane]       : 0.f;
    float z0b = (64 + lane < M0)  ? zlds[row0][64 + lane]  : 0.f;
    float z1b = (64 + lane < M1)  ? zlds[row1][64 + lane]  : 0.f;
    float z0c = (128 + lane < M0) ? zlds[row0][128 + lane] : 0.f;
    float z1c = (128 + lane < M1) ? zlds[row1][128 + lane] : 0.f;
    bool a0 = lane < M0, b0_ = 64 + lane < M0, c0_ = 128 + lane < M0;
    bool a1 = lane < M1, b1_ = 64 + lane < M1, c1_ = 128 + lane < M1;
    float s0 = (a0 ? z0a : 0.f) + (b0_ ? z0b : 0.f) + (c0_ ? z0c : 0.f);
    float n0 = (a0 ? 1.f : 0.f) + (b0_ ? 1.f : 0.f) + (c0_ ? 1.f : 0.f);
    float s1 = (a1 ? z1a : 0.f) + (b1_ ? z1b : 0.f) + (c1_ ? z1c : 0.f);
    float n1 = (a1 ? 1.f : 0.f) + (b1_ ? 1.f : 0.f) + (c1_ ? 1.f : 0.f);
    red4(s0, n0, s1, n1);
    tau0 = (s0 - 1.f) / n0; tau1 = (s1 - 1.f) / n1;
    float p0 = n0, p1 = n1;
    #pragma unroll 1
    for (int it = 0; it < 32; ++it){
      bool i0a = a0 && z0a > tau0, i0b = b0_ && z0b > tau0, i0c = c0_ && z0c > tau0;
      bool i1a = a1 && z1a > tau1, i1b = b1_ && z1b > tau1, i1c = c1_ && z1c > tau1;
      s0 = (i0a ? z0a : 0.f) + (i0b ? z0b : 0.f) + (i0c ? z0c : 0.f);
      n0 = (i0a ? 1.f : 0.f) + (i0b ? 1.f : 0.f) + (i0c ? 1.f : 0.f);
      s1 = (i1a ? z1a : 0.f) + (i1b ? z1b : 0.f) + (i1c ? z1c : 0.f);
      n1 = (i1a ? 1.f : 0.f) + (i1b ? 1.f : 0.f) + (i1c ? 1.f : 0.f);
      red4(s0, n0, s1, n1);
      bool stable = (n0 == p0) && (n1 == p1);
      tau0 = (s0 - 1.f) / n0; tau1 = (s1 - 1.f) / n1;
      p0 = n0; p1 = n1;
      if (stable) break;
    }
  }

  // dense output, vectorized: lane owns cols [qtr*256 + (lane&15)*4, +4)
  float* o0 = out + ((size_t)(rowbase + row0) * NHEAD + h) * NSEQ;
  float* o1 = out + ((size_t)(rowbase + row1) * NHEAD + h) * NSEQ;
  int b0v = (lane & 15) << 2;
  unsigned long long pmask = (1ull << b0v) - 1ull;     // b0v==0 -> 0
  #pragma unroll
  for (int qtr = 0; qtr < 4; ++qtr){
    int cw = (qtr << 2) + (lane >> 4);
    unsigned long long w0 = mw[row0][cw], w1 = mw[row1][cw];
    int rk0 = (int)mp[row0][cw] + __popcll(w0 & pmask);
    int rk1 = (int)mp[row1][cw] + __popcll(w1 & pmask);
    float v0[4], v1[4];
    #pragma unroll
    for (int j = 0; j < 4; ++j){
      int bit0 = (int)((w0 >> (b0v + j)) & 1ull);
      int bit1 = (int)((w1 >> (b0v + j)) & 1ull);
      v0[j] = bit0 ? fmaxf(zlds[row0][rk0] - tau0, 0.f) : 0.f;
      v1[j] = bit1 ? fmaxf(zlds[row1][rk1] - tau1, 0.f) : 0.f;
      rk0 += bit0; rk1 += bit1;
    }
    ((float4*)o0)[(qtr << 6) + lane] = make_float4(v0[0], v0[1], v0[2], v0[3]);
    ((float4*)o1)[(qtr << 6) + lane] = make_float4(v1[0], v1[1], v1[2], v1[3]);
  }
}

extern "C" void kernel_launch(void* const* d_in, const int* in_sizes, int n_in,
                              void* d_out, int out_size, void* d_ws, size_t ws_size,
                              hipStream_t stream) {
  const float* Q  = (const float*)d_in[0];
  const float* V  = (const float*)d_in[1];
  const float* A  = (const float*)d_in[2];
  const float* WQ = (const float*)d_in[3];
  const float* bQ = (const float*)d_in[4];
  const float* WK = (const float*)d_in[5];
  const float* bK = (const float*)d_in[6];
  float* out = (float*)d_out;

  char* ws = (char*)d_ws;
  unsigned short*     qf  = (unsigned short*)ws;                          // 6.29 MB
  unsigned short*     kf  = (unsigned short*)(ws + (size_t)6291456);      // 6.29 MB
  unsigned long long* bm  = (unsigned long long*)(ws + (size_t)12582912); // 1.05 MB
  unsigned short*     bmp = (unsigned short*)(ws + (size_t)13631488);     // 0.26 MB
  (void)in_sizes; (void)n_in; (void)out_size; (void)ws_size;

  fused_pre_kernel<<<3072, 256, 0, stream>>>(Q, V, WQ, WK, bQ, bK, A,
                                             qf, kf, bm, bmp);
  attn_kernel<<<3072, 512, 0, stream>>>(qf, kf, bm, bmp, out);
}